// Round 9
// baseline (200.239 us; speedup 1.0000x reference)
//
#include <hip/hip_runtime.h>
#include <stdint.h>

// Problem constants: B=2, S=2048, HIDDEN=1024, NH=16, D=64
// M = B*S = 4096, N1 = 3072, K = 1024, N2 = 1024, BH = 32

#define DEV static __device__ __forceinline__

typedef unsigned short u16;
typedef __attribute__((ext_vector_type(4))) float f32x4;
typedef __attribute__((ext_vector_type(16))) float f32x16;
typedef __bf16 bf16x8 __attribute__((ext_vector_type(8)));
typedef __attribute__((ext_vector_type(8))) unsigned short u16x8;
typedef __attribute__((ext_vector_type(4))) unsigned short u16x4;

// 0.125 * log2(e): folded into Q so softmax weights are exp2(acc)
#define QSCALE 0.18033688011112042f

DEV u16 f2bf(float f) {
    unsigned u = __builtin_bit_cast(unsigned, f);
    u += 0x7fffu + ((u >> 16) & 1u);
    return (u16)(u >> 16);
}
DEV float bf2f(u16 h) {
    unsigned u = ((unsigned)h) << 16;
    return __builtin_bit_cast(float, u);
}

// async global->LDS, 16B per lane. LDS dest must be wave-uniform base + lane*16.
DEV void async_copy16(const void* g, void* l) {
    __builtin_amdgcn_global_load_lds(
        (__attribute__((address_space(1))) void*)(g),
        (__attribute__((address_space(3))) void*)(l), 16, 0, 0);
}

// ---------------- prep: cast x + transpose-cast both weights ----------------
// grid partition (block-uniform branches):
//   [0,4096)      cast x (f32 -> bf16), 1 f32x4 group/thread (1M groups)
//   [4096,7168)   transpose wqkv [1024][3072] -> [3072][1024] bf16
//   [7168,8192)   transpose wo   [1024][1024] -> [1024][1024] bf16
DEV void transpose_tile(const float* __restrict__ src, u16* __restrict__ dst,
                        int rows, int cols, int bx, int by, int t, float* tile) {
    int c0 = bx * 32, r0 = by * 32;
    int tx = t & 31, ty = t >> 5;  // (32,8)
#pragma unroll
    for (int i = 0; i < 4; i++)
        tile[(ty + i * 8) * 33 + tx] = src[(size_t)(r0 + ty + i * 8) * cols + c0 + tx];
    __syncthreads();
#pragma unroll
    for (int i = 0; i < 4; i++)
        dst[(size_t)(c0 + ty + i * 8) * rows + r0 + tx] = f2bf(tile[tx * 33 + ty + i * 8]);
}

__global__ __launch_bounds__(256) void prep(
    const float* __restrict__ x, const float* __restrict__ wqkv,
    const float* __restrict__ wo, u16* __restrict__ xb,
    u16* __restrict__ wqkvT, u16* __restrict__ woT) {
    __shared__ float tile[32 * 33];
    const int gid = blockIdx.x;
    const int t = threadIdx.x;
    if (gid < 4096) {
        int i = gid * 256 + t;  // 1048576 f32x4 groups total
        f32x4 v = *(const f32x4*)(x + (size_t)i * 4);
        u16x4 o;
#pragma unroll
        for (int j = 0; j < 4; j++) o[j] = f2bf(v[j]);
        *(u16x4*)(xb + (size_t)i * 4) = o;
    } else if (gid < 7168) {
        int lid = gid - 4096;   // 3072 tiles: 96 x 32
        transpose_tile(wqkv, wqkvT, 1024, 3072, lid % 96, lid / 96, t, tile);
    } else {
        int lid = gid - 7168;   // 1024 tiles: 32 x 32
        transpose_tile(wo, woT, 1024, 1024, lid & 31, lid >> 5, t, tile);
    }
}

// ---------------- GEMM1: qkv projection ----------------
// 128x128 tile; LDS-transpose epilogue -> coalesced 16B stores into
// q/k/v [bh][s][d] bf16. Each block's n-range lies in exactly one of q/k/v.
__global__ __launch_bounds__(256) void gemm_qkv(
    const u16* __restrict__ A, const u16* __restrict__ Bt,
    u16* __restrict__ qb, u16* __restrict__ kb, u16* __restrict__ vb) {
    __shared__ __align__(16) u16 smem[128 * 136];  // 34 KB; aliases As/Bs/Cs
    u16* As = smem;            // [128][32]
    u16* Bs = smem + 4096;     // [128][32]
    const int t = threadIdx.x;
    const int wave = t >> 6;
    const int lane = t & 63;
    const int quad = lane >> 4;
    const int l16 = lane & 15;
    const int wr = wave >> 1;
    const int wc = wave & 1;
    const int m0 = blockIdx.y * 128;
    const int n0 = blockIdx.x * 128;

    f32x4 acc[4][4];
#pragma unroll
    for (int i = 0; i < 4; i++)
#pragma unroll
        for (int j = 0; j < 4; j++) acc[i][j] = {0.f, 0.f, 0.f, 0.f};

    for (int kt = 0; kt < 1024; kt += 32) {
#pragma unroll
        for (int i = 0; i < 2; i++) {
            int idx = i * 256 + t;
            int row = idx >> 2, kc = idx & 3;
            async_copy16(A + (size_t)(m0 + row) * 1024 + kt + kc * 8, &As[idx * 8]);
            async_copy16(Bt + (size_t)(n0 + row) * 1024 + kt + kc * 8, &Bs[idx * 8]);
        }
        __syncthreads();
        bf16x8 af[4], bfr[4];
#pragma unroll
        for (int mt = 0; mt < 4; mt++)
            af[mt] = *(const bf16x8*)&As[(wr * 64 + mt * 16 + l16) * 32 + quad * 8];
#pragma unroll
        for (int nt = 0; nt < 4; nt++)
            bfr[nt] = *(const bf16x8*)&Bs[(wc * 64 + nt * 16 + l16) * 32 + quad * 8];
#pragma unroll
        for (int mt = 0; mt < 4; mt++)
#pragma unroll
            for (int nt = 0; nt < 4; nt++)
                acc[mt][nt] = __builtin_amdgcn_mfma_f32_16x16x32_bf16(
                    af[mt], bfr[nt], acc[mt][nt], 0, 0, 0);
        __syncthreads();
    }

    // ---- epilogue: acc -> LDS [m][n] bf16 (stride 136) -> coalesced global
    const int tsel = n0 >> 10;  // 0=q 1=k 2=v (block-uniform)
    u16* dst = tsel == 0 ? qb : (tsel == 1 ? kb : vb);
    const float scl = tsel == 0 ? QSCALE : 1.0f;
#pragma unroll
    for (int mt = 0; mt < 4; mt++)
#pragma unroll
        for (int nt = 0; nt < 4; nt++) {
            int nn = wc * 64 + nt * 16 + l16;
#pragma unroll
            for (int r = 0; r < 4; r++) {
                int mm = wr * 64 + mt * 16 + quad * 4 + r;
                smem[mm * 136 + nn] = f2bf(acc[mt][nt][r] * scl);
            }
        }
    __syncthreads();
    const int col0 = (l16) * 8;       // 0..120 (8-aligned, within one 64-d head)
    const int rowb = (t >> 4);        // 0..15
    const int h0 = (n0 & 1023) >> 6;  // first of the block's 2 heads
#pragma unroll
    for (int i = 0; i < 8; i++) {
        int row = i * 16 + rowb;      // 0..127
        u16x8 v = *(const u16x8*)&smem[row * 136 + col0];
        int h = h0 + (col0 >> 6), d = col0 & 63;
        int mm = m0 + row;
        int b = mm >> 11, s = mm & 2047;
        *(u16x8*)&dst[((size_t)((b * 16 + h) * 2048 + s)) * 64 + d] = v;
    }
}

// ---------------- attention passes (LDS-staged, 256 rows per barrier) -------
// No max subtraction: scores are O(+-5); exp(s)/sum(exp(s)) == softmax.
// Q pre-scaled by 0.125*log2e so weights are exp2(acc).
// 32x32x16 layouts: A/B [row=lane&31][k=f*16+(lane>>5)*8+j];
// C/D col=lane&31, row=(r&3)+8*(r>>2)+4*(lane>>5).
//
// Pass 1: block = 4 waves x 32 q-rows = 128 q-rows; stages 256 k-rows
// (32 KB) per barrier pair, 4 iterations over its 1024-k chunk.
__global__ __launch_bounds__(256) void attn_pass1(
    const u16* __restrict__ qb, const u16* __restrict__ kb,
    float* __restrict__ lp) {
    __shared__ __align__(16) u16 Ks0[256 * 32];  // d 0..31
    __shared__ __align__(16) u16 Ks1[256 * 32];  // d 32..63
    const int t = threadIdx.x;
    const int wave = t >> 6;
    const int lane = t & 63;
    const int l32 = lane & 31, half = lane >> 5;
    const int kchunk = blockIdx.x & 1;
    const int qblk = (blockIdx.x >> 1) & 15;
    const int bh = blockIdx.x >> 5;
    const int q0 = qblk * 128 + wave * 32;

    // persistent Q fragments: A[m=l32][k=f*16+half*8+j]
    const u16* Qr = qb + (size_t)(bh * 2048 + q0 + l32) * 64 + half * 8;
    bf16x8 a[4];
#pragma unroll
    for (int f = 0; f < 4; f++) a[f] = *(const bf16x8*)&Qr[f * 16];

    const u16* Kbase = kb + (size_t)(bh * 2048 + kchunk * 1024) * 64;
    const int srow = t >> 2, sc = (t & 3) * 8;

    float lsum[16];
#pragma unroll
    for (int r = 0; r < 16; r++) lsum[r] = 0.f;

    for (int kt = 0; kt < 4; kt++) {
#pragma unroll
        for (int rr = 0; rr < 4; rr++) {
            const u16* src = Kbase + (size_t)(kt * 256 + rr * 64 + srow) * 64 + sc;
            async_copy16(src, &Ks0[rr * 2048 + t * 8]);
            async_copy16(src + 32, &Ks1[rr * 2048 + t * 8]);
        }
        __syncthreads();
#pragma unroll
        for (int sub = 0; sub < 8; sub++) {
            const int row = sub * 32 + l32;
            bf16x8 bfr[4];
            bfr[0] = *(const bf16x8*)&Ks0[row * 32 + half * 8];
            bfr[1] = *(const bf16x8*)&Ks0[row * 32 + 16 + half * 8];
            bfr[2] = *(const bf16x8*)&Ks1[row * 32 + half * 8];
            bfr[3] = *(const bf16x8*)&Ks1[row * 32 + 16 + half * 8];
            f32x16 acc;
#pragma unroll
            for (int r = 0; r < 16; r++) acc[r] = 0.f;
#pragma unroll
            for (int f = 0; f < 4; f++)
                acc = __builtin_amdgcn_mfma_f32_32x32x16_bf16(a[f], bfr[f], acc, 0, 0, 0);
#pragma unroll
            for (int r = 0; r < 16; r++)
                lsum[r] += __builtin_amdgcn_exp2f(acc[r]);
        }
        __syncthreads();
    }
    // reduce each row across the 32 k-columns (lanes within each half)
#pragma unroll
    for (int r = 0; r < 16; r++) {
        float v = lsum[r];
        v += __shfl_xor(v, 1);
        v += __shfl_xor(v, 2);
        v += __shfl_xor(v, 4);
        v += __shfl_xor(v, 8);
        v += __shfl_xor(v, 16);
        lsum[r] = v;
    }
    if (l32 == 0) {
        float* dst = lp + kchunk * 65536 + bh * 2048 + q0 + half * 4;
#pragma unroll
        for (int r = 0; r < 16; r++)
            dst[(r & 3) + 8 * (r >> 2)] = lsum[r];
    }
}

// Pass 2: block = 4 waves x 32 k-cols = 128 k-cols; stages 256 q-rows per
// barrier pair; li = 1/(lp0+lp1) computed once into LDS at block start.
__global__ __launch_bounds__(256) void attn_pass2(
    const u16* __restrict__ qb, const u16* __restrict__ kb,
    const float* __restrict__ lp, float* __restrict__ cp) {
    __shared__ __align__(16) u16 Qs0[256 * 32];
    __shared__ __align__(16) u16 Qs1[256 * 32];
    __shared__ __align__(16) float li_lds[1024];
    const int t = threadIdx.x;
    const int wave = t >> 6;
    const int lane = t & 63;
    const int l32 = lane & 31, half = lane >> 5;
    const int qchunk = blockIdx.x & 1;
    const int kblk = (blockIdx.x >> 1) & 15;
    const int bh = blockIdx.x >> 5;
    const int k0 = kblk * 128 + wave * 32;

    // li table for this block's q-chunk
    {
        const int base = bh * 2048 + qchunk * 1024;
        f32x4 p0 = *(const f32x4*)&lp[base + t * 4];
        f32x4 p1 = *(const f32x4*)&lp[65536 + base + t * 4];
        f32x4 li;
#pragma unroll
        for (int j = 0; j < 4; j++) li[j] = 1.0f / (p0[j] + p1[j]);
        *(f32x4*)&li_lds[t * 4] = li;
    }

    // persistent K fragments: B[n=l32][k=f*16+half*8+j]
    const u16* Kr = kb + (size_t)(bh * 2048 + k0 + l32) * 64 + half * 8;
    bf16x8 b[4];
#pragma unroll
    for (int f = 0; f < 4; f++) b[f] = *(const bf16x8*)&Kr[f * 16];

    const u16* Qbase = qb + (size_t)(bh * 2048 + qchunk * 1024) * 64;
    const int srow = t >> 2, sc = (t & 3) * 8;

    float cs = 0.f;
    __syncthreads();  // li_lds ready

    for (int qt = 0; qt < 4; qt++) {
#pragma unroll
        for (int rr = 0; rr < 4; rr++) {
            const u16* src = Qbase + (size_t)(qt * 256 + rr * 64 + srow) * 64 + sc;
            async_copy16(src, &Qs0[rr * 2048 + t * 8]);
            async_copy16(src + 32, &Qs1[rr * 2048 + t * 8]);
        }
        __syncthreads();
#pragma unroll
        for (int sub = 0; sub < 8; sub++) {
            const int row = sub * 32 + l32;
            bf16x8 af[4];
            af[0] = *(const bf16x8*)&Qs0[row * 32 + half * 8];
            af[1] = *(const bf16x8*)&Qs0[row * 32 + 16 + half * 8];
            af[2] = *(const bf16x8*)&Qs1[row * 32 + half * 8];
            af[3] = *(const bf16x8*)&Qs1[row * 32 + 16 + half * 8];
            f32x16 acc;
#pragma unroll
            for (int r = 0; r < 16; r++) acc[r] = 0.f;
#pragma unroll
            for (int f = 0; f < 4; f++)
                acc = __builtin_amdgcn_mfma_f32_32x32x16_bf16(af[f], b[f], acc, 0, 0, 0);
            const float* lr = &li_lds[qt * 256 + sub * 32 + half * 4];
            f32x4 li0 = *(const f32x4*)&lr[0];
            f32x4 li1 = *(const f32x4*)&lr[8];
            f32x4 li2 = *(const f32x4*)&lr[16];
            f32x4 li3 = *(const f32x4*)&lr[24];
#pragma unroll
            for (int r = 0; r < 4; r++) cs += __builtin_amdgcn_exp2f(acc[r]) * li0[r];
#pragma unroll
            for (int r = 0; r < 4; r++) cs += __builtin_amdgcn_exp2f(acc[4 + r]) * li1[r];
#pragma unroll
            for (int r = 0; r < 4; r++) cs += __builtin_amdgcn_exp2f(acc[8 + r]) * li2[r];
#pragma unroll
            for (int r = 0; r < 4; r++) cs += __builtin_amdgcn_exp2f(acc[12 + r]) * li3[r];
        }
        __syncthreads();
    }
    cs += __shfl_xor(cs, 32);
    if (lane < 32)
        cp[qchunk * 65536 + bh * 2048 + k0 + lane] = cs;
}

// GEMM2 (fused scale_v): out = (cs .* V_flat) @ w_o, fp32 output.
// A-tile staged via VGPR path: load vb, scale by cs = cp0+cp1, ds_write.
// 64x128 tiles -> 512 blocks (2/CU).
__global__ __launch_bounds__(256) void gemm_out(
    const u16* __restrict__ vb, const float* __restrict__ cp,
    const u16* __restrict__ Bt, float* __restrict__ out) {
    __shared__ __align__(16) u16 As[64 * 32];
    __shared__ __align__(16) u16 Bs[128 * 32];
    const int m0 = blockIdx.y * 64;
    const int n0 = blockIdx.x * 128;
    const int t = threadIdx.x;
    const int wave = t >> 6, lane = t & 63;
    const int quad = lane >> 4, l16 = lane & 15;
    const int wr = wave >> 1, wc = wave & 1;  // wave tile: 32 rows x 64 cols

    // this thread's fixed A-row coords
    const int mm = m0 + (t >> 2);
    const int b = mm >> 11, s = mm & 2047;

    f32x4 acc[2][4];
#pragma unroll
    for (int i = 0; i < 2; i++)
#pragma unroll
        for (int j = 0; j < 4; j++) acc[i][j] = {0.f, 0.f, 0.f, 0.f};

    for (int kt = 0; kt < 1024; kt += 32) {
        // A staging with fused colsum scale
        {
            int k0 = kt + (t & 3) * 8;
            int h = k0 >> 6, d = k0 & 63;
            int ci = (b * 16 + h) * 2048 + s;
            float csc = cp[ci] + cp[65536 + ci];
            u16x8 v = *(const u16x8*)&vb[((size_t)ci) * 64 + d];
            u16x8 o;
#pragma unroll
            for (int j = 0; j < 8; j++) o[j] = f2bf(bf2f(v[j]) * csc);
            *(u16x8*)&As[t * 8] = o;
        }
#pragma unroll
        for (int i = 0; i < 2; i++) {
            int idx = i * 256 + t;
            int row = idx >> 2, kc = idx & 3;
            async_copy16(Bt + (size_t)(n0 + row) * 1024 + kt + kc * 8, &Bs[idx * 8]);
        }
        __syncthreads();
        bf16x8 af[2], bfr[4];
#pragma unroll
        for (int mt = 0; mt < 2; mt++)
            af[mt] = *(const bf16x8*)&As[(wr * 32 + mt * 16 + l16) * 32 + quad * 8];
#pragma unroll
        for (int nt = 0; nt < 4; nt++)
            bfr[nt] = *(const bf16x8*)&Bs[(wc * 64 + nt * 16 + l16) * 32 + quad * 8];
#pragma unroll
        for (int mt = 0; mt < 2; mt++)
#pragma unroll
            for (int nt = 0; nt < 4; nt++)
                acc[mt][nt] = __builtin_amdgcn_mfma_f32_16x16x32_bf16(
                    af[mt], bfr[nt], acc[mt][nt], 0, 0, 0);
        __syncthreads();
    }
#pragma unroll
    for (int nt = 0; nt < 4; nt++) {
        int nn = n0 + wc * 64 + nt * 16 + l16;
#pragma unroll
        for (int mt = 0; mt < 2; mt++) {
#pragma unroll
            for (int r = 0; r < 4; r++) {
                int mr = m0 + wr * 32 + mt * 16 + quad * 4 + r;
                out[(size_t)mr * 1024 + nn] = acc[mt][nt][r];
            }
        }
    }
}

// ---------------- launch ----------------

extern "C" void kernel_launch(void* const* d_in, const int* in_sizes, int n_in,
                              void* d_out, int out_size, void* d_ws, size_t ws_size,
                              hipStream_t stream) {
    const float* x    = (const float*)d_in[0];   // [2,2048,1024]
    const float* wqkv = (const float*)d_in[1];   // [1024,3072]
    const float* wo   = (const float*)d_in[2];   // [1024,1024]
    float* out = (float*)d_out;                  // [2,2048,1024] fp32
    char* ws = (char*)d_ws;

    u16* xb      = (u16*)(ws);                   // [4096][1024] bf16 (dead after gemm_qkv)
    u16* wqkvT   = (u16*)(ws + 8388608);         // [3072][1024] bf16
    u16* woT     = (u16*)(ws + 14680064);        // [1024][1024] bf16
    u16* qb      = (u16*)(ws + 16777216);        // [32][2048][64] bf16
    u16* kb      = (u16*)(ws + 25165824);
    u16* vb      = (u16*)(ws + 33554432);
    // partial buffers alias xb (dead after gemm_qkv)
    float* lp    = (float*)(ws);                 // [2][32][2048]
    float* cp    = (float*)(ws + 1048576);       // [2][32][2048]

    prep<<<8192, 256, 0, stream>>>(x, wqkv, wo, xb, wqkvT, woT);
    gemm_qkv<<<dim3(24, 32), 256, 0, stream>>>(xb, wqkvT, qb, kb, vb);
    attn_pass1<<<1024, 256, 0, stream>>>(qb, kb, lp);
    attn_pass2<<<1024, 256, 0, stream>>>(qb, kb, lp, cp);
    gemm_out<<<dim3(8, 64), 256, 0, stream>>>(vb, cp, woT, out);
}